// Round 8
// baseline (816.528 us; speedup 1.0000x reference)
//
#include <hip/hip_runtime.h>

// Problem dims (fixed)
constexpr int T  = 512;
constexpr int NB = 64;    // batch
constexpr int NI = 128;   // input
constexpr int NH = 512;   // hidden
constexpr int NO = 64;    // output

constexpr float ALPHA = 0.2f;
constexpr float NSC   = 0.063245553203367586f; // 0.1*sqrt(2*ALPHA)

// ---------------------------------------------------------------------------
// Generic fp32 GEMM: C[M,N] = A[M,K] @ B[N,K]^T + bias[N]   (R3-proven)
__global__ __launch_bounds__(256) void k_gemm_nt_bias(
    const float* __restrict__ A, const float* __restrict__ Bm,
    const float* __restrict__ bias, float* __restrict__ C,
    int M, int N, int K)
{
    __shared__ __align__(16) float As[32][68];
    __shared__ __align__(16) float Bs[32][68];
    const int tid = threadIdx.x;
    const int tx = tid & 15, ty = tid >> 4;
    const long row0 = (long)blockIdx.x * 64;
    const long col0 = (long)blockIdx.y * 64;
    const int lr = tid >> 3;
    const int lq = tid & 7;

    float acc[4][4] = {};

    for (int kt = 0; kt < K; kt += 32) {
        #pragma unroll
        for (int hh = 0; hh < 2; ++hh) {
            const int r = lr + hh * 32;
            const float4 va = *(const float4*)&A[(size_t)(row0 + r) * K + kt + lq * 4];
            As[lq*4+0][r] = va.x; As[lq*4+1][r] = va.y;
            As[lq*4+2][r] = va.z; As[lq*4+3][r] = va.w;
            const float4 vb = *(const float4*)&Bm[(size_t)(col0 + r) * K + kt + lq * 4];
            Bs[lq*4+0][r] = vb.x; Bs[lq*4+1][r] = vb.y;
            Bs[lq*4+2][r] = vb.z; Bs[lq*4+3][r] = vb.w;
        }
        __syncthreads();
        #pragma unroll
        for (int kk = 0; kk < 32; ++kk) {
            const float4 a4 = *(const float4*)&As[kk][ty * 4];
            const float4 b4 = *(const float4*)&Bs[kk][tx * 4];
            const float a[4] = {a4.x, a4.y, a4.z, a4.w};
            const float b[4] = {b4.x, b4.y, b4.z, b4.w};
            #pragma unroll
            for (int i = 0; i < 4; ++i)
                #pragma unroll
                for (int j = 0; j < 4; ++j)
                    acc[i][j] += a[i] * b[j];
        }
        __syncthreads();
    }

    #pragma unroll
    for (int i = 0; i < 4; ++i) {
        const long r = row0 + ty * 4 + i;
        const int  cc = (int)col0 + tx * 4;
        float4 ov;
        ov.x = acc[i][0] + bias[cc + 0];
        ov.y = acc[i][1] + bias[cc + 1];
        ov.z = acc[i][2] + bias[cc + 2];
        ov.w = acc[i][3] + bias[cc + 3];
        *(float4*)&C[(size_t)r * N + cc] = ov;
    }
}

// ---------------------------------------------------------------------------
// u32 exchange word (R3-PROVEN): [31:16]=bf16(h), [15:0]=tag.
// atomic exchange to publish, atomic fetch_or(0) to poll — RELAXED+AGENT
// RMWs execute at the device coherence point (cross-XCD-safe, no cache
// maintenance in the loop).
__device__ __forceinline__ uint32_t pack_h(float h, uint32_t tag) {
    uint32_t u = __float_as_uint(h);
    uint32_t r = (u + 0x7FFFu + ((u >> 16) & 1u)) & 0xFFFF0000u;  // RNE to bf16
    return r | (tag & 0xFFFFu);
}

// ---------------------------------------------------------------------------
// Recurrent kernel, R7 structure + FORCED W register residency (the R8 fix).
//  R7 counters showed VGPR_Count=88 < the 128 W floats declared per lane:
//  the compiler rematerialized W loads inside the t-loop, streaming 256 KB
//  per WG per step from L2 (~1.5us/step, matching measurement). The opaque
//  `asm volatile("" : "+v")` on each loaded component makes the loads
//  non-rematerializable, forcing W to stay in VGPRs (budget: ~170 live
//  vs 256 cap at __launch_bounds__(512,2)).
// Everything else byte-identical to R7 (passed, absmax 0.0156):
//  256 WGs = 64 groups (1 batch) x 4 members; member m owns cols
//  [128m,128m+128); wave w owns k-chunk [64w,64w+64); lane l -> cols
//  {l, l+64}; h bf16 in LDS (8 wave-uniform b128 reads/thread);
//  u32 RMW tagged sync, 2-slot parity, budgeted spin.
__global__ __launch_bounds__(512, 2) void k_rnn(
    const float* __restrict__ W_rec,   // [H][H]
    const float* __restrict__ noise,   // [T][B][H]
    float* __restrict__ rnn,           // [T][B][H]: xin+b_rec in, h out
    uint32_t* __restrict__ ex)         // [2][B][H] tagged words
{
    const int bid = blockIdx.x;
    const int g = bid & 63;        // group == batch
    const int m = bid >> 6;        // member 0..3
    const int tid = threadIdx.x;
    const int w = tid >> 6;        // wave = k-chunk (64 k wide)
    const int l = tid & 63;        // lane -> cols {l, l+64} of slice

    __shared__ __align__(16) unsigned short hbf[NH];  // bf16 h (1 KB)
    __shared__ __align__(16) float pr[8][128];        // per-chunk partials

    // ---- W rows fp32 into registers, PINNED via opaque asm (one-time) ----
    float4 w0[16], w1[16];
    {
        const float* p0 = W_rec + (size_t)(m * 128 + l) * NH + w * 64;
        const float* p1 = W_rec + (size_t)(m * 128 + l + 64) * NH + w * 64;
        #pragma unroll
        for (int i = 0; i < 16; ++i) {
            float4 a = *(const float4*)(p0 + i * 4);
            asm volatile("" : "+v"(a.x), "+v"(a.y), "+v"(a.z), "+v"(a.w));
            w0[i] = a;
            float4 b = *(const float4*)(p1 + i * 4);
            asm volatile("" : "+v"(b.x), "+v"(b.y), "+v"(b.z), "+v"(b.w));
            w1[i] = b;
        }
    }

    const int gc = m * 128 + tid;            // epilogue col (tid<128)

    // poller mapping (tid>=128): one u32 word of one peer
    const int q    = tid - 128;              // 0..383
    const int pp   = q >> 7;                 // 0..2
    const int pm   = pp + (pp >= m ? 1 : 0); // peer member
    const int pcol = pm * 128 + (q & 127);

    // zero bf16 h
    hbf[tid] = 0;

    // fp32 h_old carried in registers (epilogue threads only)
    float hreg = 0.f;

    // prefetch t=0 xin(+b_rec)/noise
    float xin_pf = 0.f, noi_pf = 0.f;
    if (tid < 128) {
        xin_pf = rnn[(size_t)g * NH + gc];
        noi_pf = noise[(size_t)g * NH + gc];
    }
    __syncthreads();

    int alive  = 1;
    int budget = 1 << 16;   // launch-global spin budget (hang-proof)

    for (int t = 0; t < T; ++t) {
        // ---- dot: cols {l, l+64}, k in [64w, 64w+64), h from bf16 LDS ----
        float a0 = 0.f, a1 = 0.f, a2 = 0.f, a3 = 0.f;   // col l accum (split)
        float b0 = 0.f, b1 = 0.f, b2 = 0.f, b3 = 0.f;   // col l+64 accum
        {
            const uint4* hp = (const uint4*)&hbf[w * 64];  // 8 x (8 bf16)
            #pragma unroll
            for (int i = 0; i < 8; ++i) {
                const uint4 u = hp[i];                     // broadcast b128
                const float h0 = __uint_as_float(u.x << 16);
                const float h1 = __uint_as_float(u.x & 0xFFFF0000u);
                const float h2 = __uint_as_float(u.y << 16);
                const float h3 = __uint_as_float(u.y & 0xFFFF0000u);
                const float h4 = __uint_as_float(u.z << 16);
                const float h5 = __uint_as_float(u.z & 0xFFFF0000u);
                const float h6 = __uint_as_float(u.w << 16);
                const float h7 = __uint_as_float(u.w & 0xFFFF0000u);
                const float4 wa0 = w0[i * 2], wa1 = w0[i * 2 + 1];
                const float4 wb0 = w1[i * 2], wb1 = w1[i * 2 + 1];
                a0 += wa0.x * h0;  a1 += wa0.y * h1;
                a2 += wa0.z * h2;  a3 += wa0.w * h3;
                a0 += wa1.x * h4;  a1 += wa1.y * h5;
                a2 += wa1.z * h6;  a3 += wa1.w * h7;
                b0 += wb0.x * h0;  b1 += wb0.y * h1;
                b2 += wb0.z * h2;  b3 += wb0.w * h3;
                b0 += wb1.x * h4;  b1 += wb1.y * h5;
                b2 += wb1.z * h6;  b3 += wb1.w * h7;
            }
        }
        pr[w][l]      = (a0 + a1) + (a2 + a3);
        pr[w][l + 64] = (b0 + b1) + (b2 + b3);
        __syncthreads();

        const uint32_t want = (uint32_t)(t + 1);
        uint32_t* slot = ex + (size_t)(t & 1) * NB * NH;

        if (tid < 128) {
            // ---- epilogue: reduce 8 chunk-partials, update, publish ----
            float sum = 0.f;
            #pragma unroll
            for (int k = 0; k < 8; ++k) sum += pr[k][tid];
            const float hn = fmaxf(xin_pf + sum, 0.f);     // b_rec folded in xin
            const float nw = (1.f - ALPHA) * hreg + ALPHA * hn + NSC * noi_pf;
            hreg = nw;
            const uint32_t pk = pack_h(nw, want);
            (void)__hip_atomic_exchange(&slot[(size_t)g * NH + gc], pk,
                                        __ATOMIC_RELAXED, __HIP_MEMORY_SCOPE_AGENT);
            hbf[gc] = (unsigned short)(pk >> 16);          // own col, same rounding
            rnn[((size_t)t * NB + g) * NH + gc] = nw;
            const int tn = (t + 1 < T) ? (t + 1) : t;
            xin_pf = rnn[((size_t)tn * NB + g) * NH + gc];
            noi_pf = noise[((size_t)tn * NB + g) * NH + gc];
        } else {
            // ---- gather: poll one peer word via RMW ----
            uint32_t v;
            if (alive) {
                for (;;) {
                    v = __hip_atomic_fetch_or(&slot[(size_t)g * NH + pcol], 0u,
                                              __ATOMIC_RELAXED, __HIP_MEMORY_SCOPE_AGENT);
                    if ((v & 0xFFFFu) == (want & 0xFFFFu)) break;
                    __builtin_amdgcn_s_sleep(1);
                    if (--budget < 0) { alive = 0; break; }   // fail loudly
                }
            } else {
                v = __hip_atomic_fetch_or(&slot[(size_t)g * NH + pcol], 0u,
                                          __ATOMIC_RELAXED, __HIP_MEMORY_SCOPE_AGENT);
            }
            hbf[pcol] = (unsigned short)(v >> 16);
        }
        __syncthreads();
    }
}

// ---------------------------------------------------------------------------
extern "C" void kernel_launch(void* const* d_in, const int* in_sizes, int n_in,
                              void* d_out, int out_size, void* d_ws, size_t ws_size,
                              hipStream_t stream)
{
    (void)in_sizes; (void)n_in; (void)out_size; (void)ws_size;
    const float* x     = (const float*)d_in[0];
    const float* noise = (const float*)d_in[1];
    const float* W_in  = (const float*)d_in[2];
    const float* W_rec = (const float*)d_in[3];
    const float* b_rec = (const float*)d_in[4];
    const float* W_out = (const float*)d_in[5];
    const float* b_out = (const float*)d_in[6];

    float* out = (float*)d_out;                       // [T*B][O]
    float* rnn = out + (size_t)T * NB * NO;           // [T*B][H] (second output)

    uint32_t* ex = (uint32_t*)d_ws;                   // [2][B][H] = 256 KB

    // clear exchange tags (replay-deterministic; tag 0 never polled-for)
    hipMemsetAsync(ex, 0, (size_t)2 * NB * NH * sizeof(uint32_t), stream);

    // xin = x @ W_in^T + b_rec  -> written into rnn region (in-place consumed)
    hipLaunchKernelGGL(k_gemm_nt_bias, dim3((T * NB) / 64, NH / 64), dim3(256), 0, stream,
                       x, W_in, b_rec, rnn, T * NB, NH, NI);

    // sequential recurrence: 256 WGs, bf16-LDS dot, pinned-W, u32 RMW sync
    hipLaunchKernelGGL(k_rnn, dim3(256), dim3(512), 0, stream,
                       W_rec, noise, rnn, ex);

    // output = rnn @ W_out^T + b_out
    hipLaunchKernelGGL(k_gemm_nt_bias, dim3((T * NB) / 64, NO / 64), dim3(256), 0, stream,
                       rnn, W_out, b_out, out, T * NB, NO, NH);
}

// Round 9
// 732.852 us; speedup vs baseline: 1.1142x; 1.1142x over previous
//
#include <hip/hip_runtime.h>

// Problem dims (fixed)
constexpr int T  = 512;
constexpr int NB = 64;    // batch
constexpr int NI = 128;   // input
constexpr int NH = 512;   // hidden
constexpr int NO = 64;    // output

constexpr float ALPHA = 0.2f;
constexpr float NSC   = 0.063245553203367586f; // 0.1*sqrt(2*ALPHA)

typedef _Float16 h2_t __attribute__((ext_vector_type(2)));

#if defined(__has_builtin)
#  if __has_builtin(__builtin_amdgcn_fdot2)
#    define HAS_FDOT2 1
#  endif
#endif
#ifndef HAS_FDOT2
#  define HAS_FDOT2 0
#endif

// acc += dot(two f16 pairs)  — v_dot2_f32_f16 when available (1 instr, no unpack)
__device__ __forceinline__ float dot2(uint32_t wbits, uint32_t hbits, float acc) {
#if HAS_FDOT2
    return __builtin_amdgcn_fdot2(__builtin_bit_cast(h2_t, wbits),
                                  __builtin_bit_cast(h2_t, hbits), acc, false);
#else
    const h2_t wv = __builtin_bit_cast(h2_t, wbits);
    const h2_t hv = __builtin_bit_cast(h2_t, hbits);
    return acc + (float)wv.x * (float)hv.x + (float)wv.y * (float)hv.y;
#endif
}

// ---------------------------------------------------------------------------
// Generic fp32 GEMM: C[M,N] = A[M,K] @ B[N,K]^T + bias[N]   (R3-proven)
__global__ __launch_bounds__(256) void k_gemm_nt_bias(
    const float* __restrict__ A, const float* __restrict__ Bm,
    const float* __restrict__ bias, float* __restrict__ C,
    int M, int N, int K)
{
    __shared__ __align__(16) float As[32][68];
    __shared__ __align__(16) float Bs[32][68];
    const int tid = threadIdx.x;
    const int tx = tid & 15, ty = tid >> 4;
    const long row0 = (long)blockIdx.x * 64;
    const long col0 = (long)blockIdx.y * 64;
    const int lr = tid >> 3;
    const int lq = tid & 7;

    float acc[4][4] = {};

    for (int kt = 0; kt < K; kt += 32) {
        #pragma unroll
        for (int hh = 0; hh < 2; ++hh) {
            const int r = lr + hh * 32;
            const float4 va = *(const float4*)&A[(size_t)(row0 + r) * K + kt + lq * 4];
            As[lq*4+0][r] = va.x; As[lq*4+1][r] = va.y;
            As[lq*4+2][r] = va.z; As[lq*4+3][r] = va.w;
            const float4 vb = *(const float4*)&Bm[(size_t)(col0 + r) * K + kt + lq * 4];
            Bs[lq*4+0][r] = vb.x; Bs[lq*4+1][r] = vb.y;
            Bs[lq*4+2][r] = vb.z; Bs[lq*4+3][r] = vb.w;
        }
        __syncthreads();
        #pragma unroll
        for (int kk = 0; kk < 32; ++kk) {
            const float4 a4 = *(const float4*)&As[kk][ty * 4];
            const float4 b4 = *(const float4*)&Bs[kk][tx * 4];
            const float a[4] = {a4.x, a4.y, a4.z, a4.w};
            const float b[4] = {b4.x, b4.y, b4.z, b4.w};
            #pragma unroll
            for (int i = 0; i < 4; ++i)
                #pragma unroll
                for (int j = 0; j < 4; ++j)
                    acc[i][j] += a[i] * b[j];
        }
        __syncthreads();
    }

    #pragma unroll
    for (int i = 0; i < 4; ++i) {
        const long r = row0 + ty * 4 + i;
        const int  cc = (int)col0 + tx * 4;
        float4 ov;
        ov.x = acc[i][0] + bias[cc + 0];
        ov.y = acc[i][1] + bias[cc + 1];
        ov.z = acc[i][2] + bias[cc + 2];
        ov.w = acc[i][3] + bias[cc + 3];
        *(float4*)&C[(size_t)r * N + cc] = ov;
    }
}

// ---------------------------------------------------------------------------
// u32 exchange word: [31:16]=f16(h), [15:0]=tag. Same R3-proven RMW protocol
// (atomic exchange publish / fetch_or(0) poll, RELAXED+AGENT — device
// coherence point, cross-XCD-safe, no cache maintenance).
__device__ __forceinline__ uint32_t pack_h(float h, uint32_t tag) {
    const _Float16 hf = (_Float16)h;                    // RNE f32->f16
    const uint32_t hb = __builtin_bit_cast(unsigned short, hf);
    return (hb << 16) | (tag & 0xFFFFu);
}

// ---------------------------------------------------------------------------
// Recurrent kernel = R8 structure with the dot switched to f16 v_dot2.
//  256 WGs = 64 groups (1 batch) x 4 members; member m owns cols
//  [128m,128m+128); wave w owns k-chunk [64w,64w+64); lane l -> cols
//  {l, l+64}. h lives in LDS as f16 (1 KB); per thread 8 wave-uniform
//  ds_read_b128. W slice as PACKED f16: 64 VGPRs/lane (2 cols x 32 words),
//  pinned via opaque asm (R8) — now fits the 128-reg budget, no spill.
//  Dot = 64 fdot2/thread (vs ~200 VALU in R8). Sync/epilogue unchanged.
__global__ __launch_bounds__(512, 2) void k_rnn(
    const float* __restrict__ W_rec,   // [H][H]
    const float* __restrict__ noise,   // [T][B][H]
    float* __restrict__ rnn,           // [T][B][H]: xin+b_rec in, h out
    uint32_t* __restrict__ ex)         // [2][B][H] tagged words
{
    const int bid = blockIdx.x;
    const int g = bid & 63;        // group == batch
    const int m = bid >> 6;        // member 0..3
    const int tid = threadIdx.x;
    const int w = tid >> 6;        // wave = k-chunk (64 k wide)
    const int l = tid & 63;        // lane -> cols {l, l+64} of slice

    __shared__ __align__(16) unsigned short hbf[NH];  // f16 h (1 KB)
    __shared__ __align__(16) float pr[8][128];        // per-chunk partials

    // ---- W rows -> packed f16 registers, pinned (one-time) ----
    uint32_t wp0[32], wp1[32];
    {
        const float* p0 = W_rec + (size_t)(m * 128 + l) * NH + w * 64;
        const float* p1 = W_rec + (size_t)(m * 128 + l + 64) * NH + w * 64;
        #pragma unroll
        for (int i = 0; i < 16; ++i) {
            const float4 a = *(const float4*)(p0 + i * 4);
            uint32_t u0 = __builtin_bit_cast(uint32_t,
                (h2_t){(_Float16)a.x, (_Float16)a.y});
            uint32_t u1 = __builtin_bit_cast(uint32_t,
                (h2_t){(_Float16)a.z, (_Float16)a.w});
            asm volatile("" : "+v"(u0), "+v"(u1));
            wp0[i * 2] = u0; wp0[i * 2 + 1] = u1;
            const float4 b = *(const float4*)(p1 + i * 4);
            uint32_t v0 = __builtin_bit_cast(uint32_t,
                (h2_t){(_Float16)b.x, (_Float16)b.y});
            uint32_t v1 = __builtin_bit_cast(uint32_t,
                (h2_t){(_Float16)b.z, (_Float16)b.w});
            asm volatile("" : "+v"(v0), "+v"(v1));
            wp1[i * 2] = v0; wp1[i * 2 + 1] = v1;
        }
    }

    const int gc = m * 128 + tid;            // epilogue col (tid<128)

    // poller mapping (tid>=128): one u32 word of one peer
    const int q    = tid - 128;              // 0..383
    const int pp   = q >> 7;                 // 0..2
    const int pm   = pp + (pp >= m ? 1 : 0); // peer member
    const int pcol = pm * 128 + (q & 127);

    // zero f16 h
    hbf[tid] = 0;

    // fp32 h_old carried in registers (epilogue threads only)
    float hreg = 0.f;

    // prefetch t=0 xin(+b_rec)/noise
    float xin_pf = 0.f, noi_pf = 0.f;
    if (tid < 128) {
        xin_pf = rnn[(size_t)g * NH + gc];
        noi_pf = noise[(size_t)g * NH + gc];
    }
    __syncthreads();

    int alive  = 1;
    int budget = 1 << 16;   // launch-global spin budget (hang-proof)

    for (int t = 0; t < T; ++t) {
        // ---- dot: cols {l, l+64}, k in [64w,64w+64), f16 LDS + fdot2 ----
        float aA0 = 0.f, aA1 = 0.f, aB0 = 0.f, aB1 = 0.f;
        {
            const uint4* hp = (const uint4*)&hbf[w * 64];  // 8 x (8 f16)
            #pragma unroll
            for (int i = 0; i < 8; ++i) {
                const uint4 u = hp[i];                     // broadcast b128
                aA0 = dot2(wp0[i*4+0], u.x, aA0);
                aA1 = dot2(wp0[i*4+1], u.y, aA1);
                aA0 = dot2(wp0[i*4+2], u.z, aA0);
                aA1 = dot2(wp0[i*4+3], u.w, aA1);
                aB0 = dot2(wp1[i*4+0], u.x, aB0);
                aB1 = dot2(wp1[i*4+1], u.y, aB1);
                aB0 = dot2(wp1[i*4+2], u.z, aB0);
                aB1 = dot2(wp1[i*4+3], u.w, aB1);
            }
        }
        pr[w][l]      = aA0 + aA1;
        pr[w][l + 64] = aB0 + aB1;
        __syncthreads();

        const uint32_t want = (uint32_t)(t + 1);
        uint32_t* slot = ex + (size_t)(t & 1) * NB * NH;

        if (tid < 128) {
            // ---- epilogue: reduce 8 chunk-partials, update, publish ----
            float sum = 0.f;
            #pragma unroll
            for (int k = 0; k < 8; ++k) sum += pr[k][tid];
            const float hn = fmaxf(xin_pf + sum, 0.f);     // b_rec folded in xin
            const float nw = (1.f - ALPHA) * hreg + ALPHA * hn + NSC * noi_pf;
            hreg = nw;
            const uint32_t pk = pack_h(nw, want);
            (void)__hip_atomic_exchange(&slot[(size_t)g * NH + gc], pk,
                                        __ATOMIC_RELAXED, __HIP_MEMORY_SCOPE_AGENT);
            hbf[gc] = (unsigned short)(pk >> 16);          // own col, same rounding
            rnn[((size_t)t * NB + g) * NH + gc] = nw;
            const int tn = (t + 1 < T) ? (t + 1) : t;
            xin_pf = rnn[((size_t)tn * NB + g) * NH + gc];
            noi_pf = noise[((size_t)tn * NB + g) * NH + gc];
        } else {
            // ---- gather: poll one peer word via RMW ----
            uint32_t v;
            if (alive) {
                for (;;) {
                    v = __hip_atomic_fetch_or(&slot[(size_t)g * NH + pcol], 0u,
                                              __ATOMIC_RELAXED, __HIP_MEMORY_SCOPE_AGENT);
                    if ((v & 0xFFFFu) == (want & 0xFFFFu)) break;
                    __builtin_amdgcn_s_sleep(1);
                    if (--budget < 0) { alive = 0; break; }   // fail loudly
                }
            } else {
                v = __hip_atomic_fetch_or(&slot[(size_t)g * NH + pcol], 0u,
                                          __ATOMIC_RELAXED, __HIP_MEMORY_SCOPE_AGENT);
            }
            hbf[pcol] = (unsigned short)(v >> 16);
        }
        __syncthreads();
    }
}

// ---------------------------------------------------------------------------
extern "C" void kernel_launch(void* const* d_in, const int* in_sizes, int n_in,
                              void* d_out, int out_size, void* d_ws, size_t ws_size,
                              hipStream_t stream)
{
    (void)in_sizes; (void)n_in; (void)out_size; (void)ws_size;
    const float* x     = (const float*)d_in[0];
    const float* noise = (const float*)d_in[1];
    const float* W_in  = (const float*)d_in[2];
    const float* W_rec = (const float*)d_in[3];
    const float* b_rec = (const float*)d_in[4];
    const float* W_out = (const float*)d_in[5];
    const float* b_out = (const float*)d_in[6];

    float* out = (float*)d_out;                       // [T*B][O]
    float* rnn = out + (size_t)T * NB * NO;           // [T*B][H] (second output)

    uint32_t* ex = (uint32_t*)d_ws;                   // [2][B][H] = 256 KB

    // clear exchange tags (replay-deterministic; tag 0 never polled-for)
    hipMemsetAsync(ex, 0, (size_t)2 * NB * NH * sizeof(uint32_t), stream);

    // xin = x @ W_in^T + b_rec  -> written into rnn region (in-place consumed)
    hipLaunchKernelGGL(k_gemm_nt_bias, dim3((T * NB) / 64, NH / 64), dim3(256), 0, stream,
                       x, W_in, b_rec, rnn, T * NB, NH, NI);

    // sequential recurrence: 256 WGs, f16 fdot2 dot, u32 RMW sync
    hipLaunchKernelGGL(k_rnn, dim3(256), dim3(512), 0, stream,
                       W_rec, noise, rnn, ex);

    // output = rnn @ W_out^T + b_out
    hipLaunchKernelGGL(k_gemm_nt_bias, dim3((T * NB) / 64, NO / 64), dim3(256), 0, stream,
                       rnn, W_out, b_out, out, T * NB, NO, NH);
}